// Round 1
// 191.765 us; speedup vs baseline: 1.0002x; 1.0002x over previous
//
#include <hip/hip_runtime.h>
#include <stdint.h>

// x [3,5,32,64,32,32] binary float -> per 32x32 image max(component size, bg count)
// -> sum over 64 patches >> 6 -> float [480].
//
// TWO images per wave: lanes 0-31 own image A's rows, lanes 32-63 image B's.
// Row-per-lane bitmasks (input exactly 0.0f/1.0f -> pixel = floatbits>>29).
// Runs numbered by segmented 64-lane scan (fg popcount packed into the same
// scan, high 16 bits). Edge phase: lock-free union with atomicCAS hooking
// LARGER ROOT -> SMALLER ROOT; JOINT dual-chain find with path halving +
// current-run root caches for BOTH endpoints (lower and upper row runs).
// Count phase: register-lean per-run loop (2-level resolve + rare findH
// fallback, then atomicAdd of run length into root; L[r] = r | size<<9).
// Wave-lockstep => no barriers. __launch_bounds__(256,8) pins 8 waves/EU
// (<=64 VGPR) so dependent-LDS latency in find chains is TLP-hidden.

#define N_IMGS 30720
#define N_OUT  480
#define WAVES_PER_BLOCK 4
#define IMGS_PER_BLOCK (WAVES_PER_BLOCK * 2)   // 8

// Serial find with path halving (used only on rare CAS-retry / deep paths).
__device__ __forceinline__ int findH(int* L, int i) {
    for (;;) {
        int p = L[i] & 511;
        if (p == i) return i;
        int g = L[p] & 511;
        if (g == p) return p;
        L[i] = g;          // halving: shortcut to grandparent (monotone-safe)
        i = g;
    }
}

__global__ __launch_bounds__(256, 8)
void ccl_wave2_kernel(const uint32_t* __restrict__ x, int* __restrict__ maxc) {
    __shared__ int Lbuf[IMGS_PER_BLOCK * 512];   // 16 KiB

    const int lane = threadIdx.x & 63;
    const int wv   = threadIdx.x >> 6;
    const int half = lane >> 5;                  // 0: image A, 1: image B
    const int row  = lane & 31;
    const size_t img = (size_t)blockIdx.x * IMGS_PER_BLOCK + wv * 2 + half;
    int* L = Lbuf + (wv * 2 + half) * 512;

    // ---- row-per-lane load: 8 x uint4 = 32 pixels; 1.0f bits >>29 == 1 ----
    const uint4* rp = (const uint4*)(x + img * 1024 + row * 32);
    uint32_t m = 0;
    #pragma unroll
    for (int i = 0; i < 8; ++i) {
        uint4 q = rp[i];
        m |= (q.x >> 29) << (4 * i + 0);
        m |= (q.y >> 29) << (4 * i + 1);
        m |= (q.z >> 29) << (4 * i + 2);
        m |= (q.w >> 29) << (4 * i + 3);
    }

    // ---- run numbering + fg count: ONE 64-lane inclusive scan, segmented at
    // lane 32. Packed word: low 16 = run count, high 16 = popcount (no field
    // overflow: runs <= 1024 total, fg <= 2048 total). ----
    uint32_t runStarts = m & ~(m << 1);
    int nruns = __popc(runStarts);
    int packed = nruns | (__popc(m) << 16);
    int scan = packed;
    #pragma unroll
    for (int off = 1; off < 64; off <<= 1) {
        int u = __shfl_up(scan, off);
        if (lane >= off) scan += u;
    }
    const int totalA   = __shfl(scan, 31);
    const int totalAll = __shfl(scan, 63);
    const int myTotal  = half ? (totalAll - totalA) : totalA;
    // low fields never borrow (inclusive scan >= own; half-B scan >= totalA)
    const int base = (scan - packed - (half ? totalA : 0)) & 0xFFFF;
    const int R    = myTotal & 0xFFFF;           // runs in my image
    const int fg   = myTotal >> 16;              // foreground pixels, my image

    for (int i = row; i < R; i += 32) L[i] = i;  // bank-conflict-free init

    // ---- edges: one per overlap segment with previous row ----
    uint32_t mprev  = __shfl_up(m, 1);
    uint32_t rsPrev = __shfl_up(runStarts, 1);
    int      bPrev  = __shfl_up(base, 1);
    if (row == 0) mprev = 0;                 // row 0 of each image
    uint32_t ov  = m & mprev;
    uint32_t ovs = ov & ~(ov << 1);

    int lastA = -1, rootA = -1;              // cache: root of current lower run
    int lastB = -1, rootB = -1;              // cache: root of current upper run
    while (ovs) {
        int c = __ffs(ovs) - 1; ovs &= ovs - 1;
        uint32_t mc = (2u << c) - 1;         // bits 0..c (c=31 -> all ones)
        int a = base  + __popc(runStarts & mc) - 1;
        int b = bPrev + __popc(rsPrev    & mc) - 1;

        int ra = (a == lastA) ? rootA : a;   // reuse merged roots if same run
        int rb = (b == lastB) ? rootB : b;
        // joint dual-chain find: both chains advance 2 levels per iteration;
        // the 4 LDS reads are independent and pipeline in the queue.
        for (;;) {
            int pa = L[ra] & 511;
            int pb = L[rb] & 511;
            if (pa == ra && pb == rb) break;
            int ga = L[pa] & 511;            // grandparents (independent)
            int gb = L[pb] & 511;
            if (pa != ra) { L[ra] = ga; ra = ga; }
            if (pb != rb) { L[rb] = gb; rb = gb; }
        }
        while (ra != rb) {                   // hook larger ROOT to smaller
            int hi = ra > rb ? ra : rb;
            int lo = ra ^ rb ^ hi;
            int old = atomicCAS(&L[hi], hi, lo);
            if (old == hi) { ra = lo; break; }   // hooked; merged root = lo
            ra = findH(L, old & 511);        // root moved; chase and retry
            rb = lo;
        }
        lastA = a; rootA = ra; lastB = b; rootB = ra;
    }
    // wave reconverges here: all unions complete before any lane proceeds.

    // ---- count phase: per-run resolve (2-level + rare fallback) + size add.
    // Register-lean: no staging array; roots are depth<=1 almost always after
    // hook-to-smaller + halving, so the chain is 2 LDS reads in the common
    // case. L[r] = r | (size<<9); adds never touch low 9 bits. ----
    uint32_t mm = m;
    int idx = base;
    while (mm) {
        int s = __ffs(mm) - 1;
        uint32_t t  = mm + (1u << s);
        uint32_t rm = (t ^ mm) & mm;         // this run's bits
        mm &= ~rm;
        int r0 = L[idx] & 511;               // level 1
        int r1 = L[r0] & 511;                // level 2
        if (r1 != r0) r1 = findH(L, r1);     // rare deep fallback
        atomicAdd(&L[r1], __popc(rm) << 9);
        ++idx;
    }

    // ---- max component size, per image (strided, conflict-free) ----
    int mx = 0;
    for (int i = row; i < R; i += 32) {
        int v = L[i];
        if ((v & 511) == i) mx = max(mx, v >> 9);
    }
    #pragma unroll
    for (int off = 1; off < 32; off <<= 1) mx = max(mx, __shfl_xor(mx, off));

    if (row == 0) maxc[img] = max(mx, 1024 - fg);
}

__global__ __launch_bounds__(64)
void patch_reduce_kernel(const int* __restrict__ maxc, float* __restrict__ out) {
    const int o = blockIdx.x;   // 0..479
    int v = maxc[(size_t)o * 64 + threadIdx.x];
    #pragma unroll
    for (int off = 32; off > 0; off >>= 1)
        v += __shfl_down(v, off);
    if (threadIdx.x == 0) out[o] = (float)(v >> 6);  // integer division by 64
}

extern "C" void kernel_launch(void* const* d_in, const int* in_sizes, int n_in,
                              void* d_out, int out_size, void* d_ws, size_t ws_size,
                              hipStream_t stream) {
    const uint32_t* x = (const uint32_t*)d_in[0];   // float bits; 1.0f>>29 == 1
    float* out = (float*)d_out;
    int* maxc = (int*)d_ws;   // 30720 ints

    ccl_wave2_kernel<<<N_IMGS / IMGS_PER_BLOCK, 256, 0, stream>>>(x, maxc);
    patch_reduce_kernel<<<N_OUT, 64, 0, stream>>>(maxc, out);
}

// Round 2
// 189.612 us; speedup vs baseline: 1.0116x; 1.0114x over previous
//
#include <hip/hip_runtime.h>
#include <stdint.h>

// x [3,5,32,64,32,32] binary float -> per 32x32 image max(component size, bg count)
// -> sum over 64 patches >> 6 -> float [480].
//
// TWO images per wave: lanes 0-31 own image A's rows, lanes 32-63 image B's.
// Row-per-lane bitmasks (input exactly 0.0f/1.0f -> pixel = floatbits>>29).
//
// LOAD: fully coalesced. Load instr j reads words pairBase + j*256 + lane*4
// (contiguous 1 KB per wave per instruction -> 16 cache lines, not 64 as with
// row-per-lane strided loads). Each uint4 packs to a 4-bit nibble; 8 nibbles
// accumulate into one word W per lane. Redistribution to row-per-lane masks:
// owner lane L's pixel p=L*32+k sits in instr j=L>>3, source lane
// sl=(L&7)*8+(k>>2), nibble bit k&3  =>  m = sum_t (shfl(W, (L&7)*8+t)
// >> 4*(L>>3) & 0xF) << 4t. 8 shuffles + shifts, cheaper than the old pack.
//
// Runs numbered by segmented 64-lane scan (fg popcount packed into the same
// scan, high 16 bits). Edge phase: lock-free union with atomicCAS hooking
// LARGER ROOT -> SMALLER ROOT; JOINT dual-chain find with path halving +
// current-run root caches for BOTH endpoints. Count phase: register-lean
// per-run loop (2-level resolve + rare findH fallback, then atomicAdd of run
// length into root; L[r] = r | size<<9). Wave-lockstep => no barriers.

#define N_IMGS 30720
#define N_OUT  480
#define WAVES_PER_BLOCK 4
#define IMGS_PER_BLOCK (WAVES_PER_BLOCK * 2)   // 8

// Serial find with path halving (used only on rare CAS-retry / deep paths).
__device__ __forceinline__ int findH(int* L, int i) {
    for (;;) {
        int p = L[i] & 511;
        if (p == i) return i;
        int g = L[p] & 511;
        if (g == p) return p;
        L[i] = g;          // halving: shortcut to grandparent (monotone-safe)
        i = g;
    }
}

__global__ __launch_bounds__(256, 8)
void ccl_wave2_kernel(const uint32_t* __restrict__ x, int* __restrict__ maxc) {
    __shared__ int Lbuf[IMGS_PER_BLOCK * 512];   // 16 KiB

    const int lane = threadIdx.x & 63;
    const int wv   = threadIdx.x >> 6;
    const int half = lane >> 5;                  // 0: image A, 1: image B
    const int row  = lane & 31;
    const size_t img = (size_t)blockIdx.x * IMGS_PER_BLOCK + wv * 2 + half;
    int* L = Lbuf + (wv * 2 + half) * 512;

    // ---- coalesced load + nibble pack: 8 x uint4, 1 KB/wave/instr ----
    const size_t pairBase = ((size_t)blockIdx.x * IMGS_PER_BLOCK + wv * 2) * 1024;
    const uint4* wp = (const uint4*)(x + pairBase) + lane;
    uint32_t W = 0;
    #pragma unroll
    for (int j = 0; j < 8; ++j) {
        uint4 q = wp[j * 64];                    // words pairBase + j*256 + lane*4
        uint32_t n = (q.x >> 29) | ((q.y >> 29) << 1)
                   | ((q.z >> 29) << 2) | ((q.w >> 29) << 3);
        W |= n << (4 * j);
    }

    // ---- repack to row-per-lane: 8 shuffles + shifts ----
    const int slBase = (lane & 7) * 8;           // first source lane
    const int jsh    = (lane >> 3) * 4;          // my instr's nibble shift
    uint32_t m = 0;
    #pragma unroll
    for (int t = 0; t < 8; ++t) {
        uint32_t sv = (uint32_t)__shfl((int)W, slBase + t);
        m |= ((sv >> jsh) & 0xFu) << (4 * t);
    }

    // ---- run numbering + fg count: ONE 64-lane inclusive scan, segmented at
    // lane 32. Packed word: low 16 = run count, high 16 = popcount. ----
    uint32_t runStarts = m & ~(m << 1);
    int nruns = __popc(runStarts);
    int packed = nruns | (__popc(m) << 16);
    int scan = packed;
    #pragma unroll
    for (int off = 1; off < 64; off <<= 1) {
        int u = __shfl_up(scan, off);
        if (lane >= off) scan += u;
    }
    const int totalA   = __shfl(scan, 31);
    const int totalAll = __shfl(scan, 63);
    const int myTotal  = half ? (totalAll - totalA) : totalA;
    // low fields never borrow (inclusive scan >= own; half-B scan >= totalA)
    const int base = (scan - packed - (half ? totalA : 0)) & 0xFFFF;
    const int R    = myTotal & 0xFFFF;           // runs in my image
    const int fg   = myTotal >> 16;              // foreground pixels, my image

    for (int i = row; i < R; i += 32) L[i] = i;  // bank-conflict-free init

    // ---- edges: one per overlap segment with previous row ----
    uint32_t mprev  = __shfl_up(m, 1);
    uint32_t rsPrev = __shfl_up(runStarts, 1);
    int      bPrev  = __shfl_up(base, 1);
    if (row == 0) mprev = 0;                 // row 0 of each image
    uint32_t ov  = m & mprev;
    uint32_t ovs = ov & ~(ov << 1);

    int lastA = -1, rootA = -1;              // cache: root of current lower run
    int lastB = -1, rootB = -1;              // cache: root of current upper run
    while (ovs) {
        int c = __ffs(ovs) - 1; ovs &= ovs - 1;
        uint32_t mc = (2u << c) - 1;         // bits 0..c (c=31 -> all ones)
        int a = base  + __popc(runStarts & mc) - 1;
        int b = bPrev + __popc(rsPrev    & mc) - 1;

        int ra = (a == lastA) ? rootA : a;   // reuse merged roots if same run
        int rb = (b == lastB) ? rootB : b;
        // joint dual-chain find: both chains advance 2 levels per iteration;
        // the 4 LDS reads are independent and pipeline in the queue.
        for (;;) {
            int pa = L[ra] & 511;
            int pb = L[rb] & 511;
            if (pa == ra && pb == rb) break;
            int ga = L[pa] & 511;            // grandparents (independent)
            int gb = L[pb] & 511;
            if (pa != ra) { L[ra] = ga; ra = ga; }
            if (pb != rb) { L[rb] = gb; rb = gb; }
        }
        while (ra != rb) {                   // hook larger ROOT to smaller
            int hi = ra > rb ? ra : rb;
            int lo = ra ^ rb ^ hi;
            int old = atomicCAS(&L[hi], hi, lo);
            if (old == hi) { ra = lo; break; }   // hooked; merged root = lo
            ra = findH(L, old & 511);        // root moved; chase and retry
            rb = lo;
        }
        lastA = a; rootA = ra; lastB = b; rootB = ra;
    }
    // wave reconverges here: all unions complete before any lane proceeds.

    // ---- count phase: per-run resolve (2-level + rare fallback) + size add.
    // L[r] = r | (size<<9); adds never touch low 9 bits. ----
    uint32_t mm = m;
    int idx = base;
    while (mm) {
        int s = __ffs(mm) - 1;
        uint32_t t  = mm + (1u << s);
        uint32_t rm = (t ^ mm) & mm;         // this run's bits
        mm &= ~rm;
        int r0 = L[idx] & 511;               // level 1
        int r1 = L[r0] & 511;                // level 2
        if (r1 != r0) r1 = findH(L, r1);     // rare deep fallback
        atomicAdd(&L[r1], __popc(rm) << 9);
        ++idx;
    }

    // ---- max component size, per image (strided, conflict-free) ----
    int mx = 0;
    for (int i = row; i < R; i += 32) {
        int v = L[i];
        if ((v & 511) == i) mx = max(mx, v >> 9);
    }
    #pragma unroll
    for (int off = 1; off < 32; off <<= 1) mx = max(mx, __shfl_xor(mx, off));

    if (row == 0) maxc[img] = max(mx, 1024 - fg);
}

__global__ __launch_bounds__(64)
void patch_reduce_kernel(const int* __restrict__ maxc, float* __restrict__ out) {
    const int o = blockIdx.x;   // 0..479
    int v = maxc[(size_t)o * 64 + threadIdx.x];
    #pragma unroll
    for (int off = 32; off > 0; off >>= 1)
        v += __shfl_down(v, off);
    if (threadIdx.x == 0) out[o] = (float)(v >> 6);  // integer division by 64
}

extern "C" void kernel_launch(void* const* d_in, const int* in_sizes, int n_in,
                              void* d_out, int out_size, void* d_ws, size_t ws_size,
                              hipStream_t stream) {
    const uint32_t* x = (const uint32_t*)d_in[0];   // float bits; 1.0f>>29 == 1
    float* out = (float*)d_out;
    int* maxc = (int*)d_ws;   // 30720 ints

    ccl_wave2_kernel<<<N_IMGS / IMGS_PER_BLOCK, 256, 0, stream>>>(x, maxc);
    patch_reduce_kernel<<<N_OUT, 64, 0, stream>>>(maxc, out);
}